// Round 1
// baseline (825.891 us; speedup 1.0000x reference)
//
#include <hip/hip_runtime.h>
#include <math.h>

#define N 8192
#define FIN 29
#define FH 8
#define NH 4
#define ALPHA 0.2f

// ---------------- K1: h = x@W, f1 = h@a1, f2 = h@a2 for 4 heads ----------------
// rec1[j][40] = { f2[0..3], h[0][0..7], h[1][0..7], h[2][0..7], h[3][0..7], pad[4] }
__global__ void k1_feat(const float* __restrict__ x, const float* __restrict__ Wh,
                        const float* __restrict__ ah,
                        float* __restrict__ rec1, float* __restrict__ f1a) {
    __shared__ float sW[NH * FIN * FH];   // 928
    __shared__ float sa[NH * 2 * FH];     // 64
    int tid = threadIdx.x;
    for (int i = tid; i < NH * FIN * FH; i += blockDim.x) sW[i] = Wh[i];
    for (int i = tid; i < NH * 2 * FH; i += blockDim.x) sa[i] = ah[i];
    __syncthreads();
    int node = blockIdx.x * blockDim.x + tid;
    if (node >= N) return;
    float xr[FIN];
#pragma unroll
    for (int f = 0; f < FIN; f++) xr[f] = x[node * FIN + f];
#pragma unroll
    for (int h = 0; h < NH; h++) {
        float hv[FH];
#pragma unroll
        for (int k = 0; k < FH; k++) {
            float s = 0.f;
#pragma unroll
            for (int f = 0; f < FIN; f++) s += xr[f] * sW[(h * FIN + f) * FH + k];
            hv[k] = s;
        }
        float f1 = 0.f, f2 = 0.f;
#pragma unroll
        for (int k = 0; k < FH; k++) {
            f1 += hv[k] * sa[h * 16 + k];
            f2 += hv[k] * sa[h * 16 + 8 + k];
        }
        rec1[node * 40 + h] = f2;
#pragma unroll
        for (int k = 0; k < FH; k++) rec1[node * 40 + 4 + h * 8 + k] = hv[k];
        f1a[node * 4 + h] = f1;
    }
}

// ---------------- K2: per-head global max of f2 (single block) ----------------
__global__ void k2_max4(const float* __restrict__ rec1, float* __restrict__ maxf2) {
    __shared__ float red[4][256];
    int tid = threadIdx.x;
    float m[4] = {-1e30f, -1e30f, -1e30f, -1e30f};
    for (int j = tid; j < N; j += 256) {
#pragma unroll
        for (int h = 0; h < 4; h++) m[h] = fmaxf(m[h], rec1[j * 40 + h]);
    }
#pragma unroll
    for (int h = 0; h < 4; h++) red[h][tid] = m[h];
    __syncthreads();
    for (int s = 128; s > 0; s >>= 1) {
        if (tid < s) {
#pragma unroll
            for (int h = 0; h < 4; h++) red[h][tid] = fmaxf(red[h][tid], red[h][tid + s]);
        }
        __syncthreads();
    }
    if (tid < 4) maxf2[tid] = red[tid][0];
}

// ---------------- K3: layer-1 attention, 8 waves x 2 rows = 16 rows/block ----------------
#define TJ 256
__global__ __launch_bounds__(512) void k3_attn1(
    const int* __restrict__ adj, const float* __restrict__ rec1,
    const float* __restrict__ f1a, const float* __restrict__ maxf2,
    float* __restrict__ hcat) {
    __shared__ float tile[TJ * 40];  // 40 KB
    int tid = threadIdx.x;
    int lane = tid & 63;
    int wave = tid >> 6;
    int r0 = blockIdx.x * 16 + wave * 2;
    int r1 = r0 + 1;

    float f1_0[NH], f1_1[NH], m0[NH], m1[NH];
#pragma unroll
    for (int h = 0; h < NH; h++) {
        f1_0[h] = f1a[r0 * 4 + h];
        f1_1[h] = f1a[r1 * 4 + h];
        float mf = maxf2[h];
        float v0 = f1_0[h] + mf; m0[h] = fmaxf(v0, ALPHA * v0);
        float v1 = f1_1[h] + mf; m1[h] = fmaxf(v1, ALPHA * v1);
    }
    float acc0[NH][FH + 1], acc1[NH][FH + 1];
#pragma unroll
    for (int h = 0; h < NH; h++)
#pragma unroll
        for (int k = 0; k <= FH; k++) { acc0[h][k] = 0.f; acc1[h][k] = 0.f; }

    for (int t = 0; t < N / TJ; t++) {
        __syncthreads();
        const float4* src = (const float4*)(rec1 + (size_t)t * TJ * 40);
        float4* dst = (float4*)tile;
#pragma unroll
        for (int i = 0; i < (TJ * 40 / 4) / 512; i++)  // 5
            dst[tid + i * 512] = src[tid + i * 512];
        __syncthreads();
#pragma unroll
        for (int s = 0; s < TJ / 64; s++) {  // 4
            int j = t * TJ + s * 64 + lane;
            int a0 = adj[r0 * N + j];
            int a1 = adj[r1 * N + j];
            const float4* rp = (const float4*)&tile[(s * 64 + lane) * 40];
            float rv[36];
#pragma unroll
            for (int i = 0; i < 9; i++) {
                float4 q = rp[i];
                rv[4 * i + 0] = q.x; rv[4 * i + 1] = q.y;
                rv[4 * i + 2] = q.z; rv[4 * i + 3] = q.w;
            }
#pragma unroll
            for (int h = 0; h < NH; h++) {
                float e0 = f1_0[h] + rv[h]; e0 = fmaxf(e0, ALPHA * e0);
                float e1 = f1_1[h] + rv[h]; e1 = fmaxf(e1, ALPHA * e1);
                float w0 = (a0 > 0) ? __expf(e0 - m0[h]) : 0.f;
                float w1 = (a1 > 0) ? __expf(e1 - m1[h]) : 0.f;
#pragma unroll
                for (int k = 0; k < FH; k++) {
                    acc0[h][k] += w0 * rv[4 + h * 8 + k];
                    acc1[h][k] += w1 * rv[4 + h * 8 + k];
                }
                acc0[h][FH] += w0;
                acc1[h][FH] += w1;
            }
        }
    }
    // butterfly reduce across 64 lanes
#pragma unroll
    for (int h = 0; h < NH; h++)
#pragma unroll
        for (int k = 0; k <= FH; k++) {
            for (int off = 32; off > 0; off >>= 1) {
                acc0[h][k] += __shfl_xor(acc0[h][k], off, 64);
                acc1[h][k] += __shfl_xor(acc1[h][k], off, 64);
            }
        }
    if (lane == 0) {
#pragma unroll
        for (int h = 0; h < NH; h++) {
            float inv0 = 1.f / acc0[h][FH];
            float inv1 = 1.f / acc1[h][FH];
#pragma unroll
            for (int k = 0; k < FH; k++) {
                float o0 = acc0[h][k] * inv0;
                float o1 = acc1[h][k] * inv1;
                o0 = (o0 > 0.f) ? o0 : expm1f(o0);
                o1 = (o1 > 0.f) ? o1 : expm1f(o1);
                hcat[r0 * 32 + h * 8 + k] = o0;
                hcat[r1 * 32 + h * 8 + k] = o1;
            }
        }
    }
}

// ---------------- K4: layer-2 features: h2 = hcat@W_out, f1/f2 ----------------
// rec2[j] = float4{ f2, h2[0], h2[1], 0 }
__global__ void k4_feat2(const float* __restrict__ hcat, const float* __restrict__ Wo,
                         const float* __restrict__ ao,
                         float4* __restrict__ rec2, float* __restrict__ f1b) {
    __shared__ float sW[64];
    __shared__ float sa[4];
    int tid = threadIdx.x;
    if (tid < 64) sW[tid] = Wo[tid];
    if (tid < 4) sa[tid] = ao[tid];
    __syncthreads();
    int node = blockIdx.x * blockDim.x + tid;
    if (node >= N) return;
    float h0 = 0.f, h1 = 0.f;
#pragma unroll
    for (int i = 0; i < 32; i++) {
        float v = hcat[node * 32 + i];
        h0 += v * sW[i * 2 + 0];
        h1 += v * sW[i * 2 + 1];
    }
    float f1 = h0 * sa[0] + h1 * sa[1];
    float f2 = h0 * sa[2] + h1 * sa[3];
    rec2[node] = make_float4(f2, h0, h1, 0.f);
    f1b[node] = f1;
}

// ---------------- K5: global max of f2 (layer 2) ----------------
__global__ void k5_max1(const float4* __restrict__ rec2, float* __restrict__ maxf2b) {
    __shared__ float red[256];
    int tid = threadIdx.x;
    float m = -1e30f;
    for (int j = tid; j < N; j += 256) m = fmaxf(m, rec2[j].x);
    red[tid] = m;
    __syncthreads();
    for (int s = 128; s > 0; s >>= 1) {
        if (tid < s) red[tid] = fmaxf(red[tid], red[tid + s]);
        __syncthreads();
    }
    if (tid == 0) maxf2b[0] = red[0];
}

// ---------------- K6: layer-2 attention + elu + log_softmax ----------------
#define TJ2 1024
__global__ __launch_bounds__(512) void k6_attn2(
    const int* __restrict__ adj, const float4* __restrict__ rec2,
    const float* __restrict__ f1b, const float* __restrict__ maxf2b,
    float* __restrict__ out) {
    __shared__ float4 tile[TJ2];  // 16 KB
    int tid = threadIdx.x;
    int lane = tid & 63;
    int wave = tid >> 6;
    int rbase = blockIdx.x * 32 + wave * 4;

    float f1r[4], mr[4];
#pragma unroll
    for (int i = 0; i < 4; i++) {
        f1r[i] = f1b[rbase + i];
        float v = f1r[i] + maxf2b[0];
        mr[i] = fmaxf(v, ALPHA * v);
    }
    float acc[4][3];
#pragma unroll
    for (int i = 0; i < 4; i++) { acc[i][0] = 0.f; acc[i][1] = 0.f; acc[i][2] = 0.f; }

    for (int t = 0; t < N / TJ2; t++) {  // 8
        __syncthreads();
#pragma unroll
        for (int i = 0; i < TJ2 / 512; i++)  // 2
            tile[tid + i * 512] = rec2[t * TJ2 + tid + i * 512];
        __syncthreads();
#pragma unroll 4
        for (int s = 0; s < TJ2 / 64; s++) {  // 16
            int j = t * TJ2 + s * 64 + lane;
            float4 q = tile[s * 64 + lane];
#pragma unroll
            for (int i = 0; i < 4; i++) {
                int a = adj[(rbase + i) * N + j];
                float e = f1r[i] + q.x;
                e = fmaxf(e, ALPHA * e);
                float w = (a > 0) ? __expf(e - mr[i]) : 0.f;
                acc[i][0] += w * q.y;
                acc[i][1] += w * q.z;
                acc[i][2] += w;
            }
        }
    }
#pragma unroll
    for (int i = 0; i < 4; i++)
#pragma unroll
        for (int c = 0; c < 3; c++)
            for (int off = 32; off > 0; off >>= 1)
                acc[i][c] += __shfl_xor(acc[i][c], off, 64);
    if (lane == 0) {
#pragma unroll
        for (int i = 0; i < 4; i++) {
            float inv = 1.f / acc[i][2];
            float e0 = acc[i][0] * inv;
            float e1 = acc[i][1] * inv;
            e0 = (e0 > 0.f) ? e0 : expm1f(e0);
            e1 = (e1 > 0.f) ? e1 : expm1f(e1);
            float mx = fmaxf(e0, e1);
            float lse = mx + logf(__expf(e0 - mx) + __expf(e1 - mx));
            out[(rbase + i) * 2 + 0] = e0 - lse;
            out[(rbase + i) * 2 + 1] = e1 - lse;
        }
    }
}

extern "C" void kernel_launch(void* const* d_in, const int* in_sizes, int n_in,
                              void* d_out, int out_size, void* d_ws, size_t ws_size,
                              hipStream_t stream) {
    const float* x  = (const float*)d_in[0];
    const int*   adj = (const int*)d_in[1];
    const float* Wh = (const float*)d_in[2];
    const float* ah = (const float*)d_in[3];
    const float* Wo = (const float*)d_in[4];
    const float* ao = (const float*)d_in[5];
    float* out = (float*)d_out;
    float* ws = (float*)d_ws;

    float*  rec1 = ws;                 // N*40 = 327680
    float*  f1a  = ws + 327680;        // N*4  = 32768
    float*  hcat = ws + 360448;        // N*32 = 262144
    float4* rec2 = (float4*)(ws + 622592);  // N*4 = 32768 floats
    float*  f1b  = ws + 655360;        // N
    float*  mf2  = ws + 663552;        // 4
    float*  mf2b = ws + 663556;        // 1

    k1_feat<<<N / 256, 256, 0, stream>>>(x, Wh, ah, rec1, f1a);
    k2_max4<<<1, 256, 0, stream>>>(rec1, mf2);
    k3_attn1<<<N / 16, 512, 0, stream>>>(adj, rec1, f1a, mf2, hcat);
    k4_feat2<<<N / 256, 256, 0, stream>>>(hcat, Wo, ao, rec2, f1b);
    k5_max1<<<1, 256, 0, stream>>>(rec2, mf2b);
    k6_attn2<<<N / 32, 512, 0, stream>>>(adj, rec2, f1b, mf2b, out);
}

// Round 2
// 652.226 us; speedup vs baseline: 1.2663x; 1.2663x over previous
//
#include <hip/hip_runtime.h>
#include <math.h>

#define N 8192
#define NW (N / 64)      // 128 mask words per row
#define FIN 29
#define FH 8
#define NH 4
#define ALPHA 0.2f

// ---------------- K0: pack adj (int32, 256 MB) into bitmask (8 MB) ----------------
// one block (256 thr) per row; coalesced 1024-int reads; __ballot -> uint64
__global__ void k0_pack(const int* __restrict__ adj, unsigned long long* __restrict__ mask) {
    int row = blockIdx.x;
    int tid = threadIdx.x;
    int lane = tid & 63;
    int wave = tid >> 6;
    const int* rp = adj + (size_t)row * N;
#pragma unroll
    for (int i = 0; i < N / 1024; i++) {   // 8
        int a = rp[i * 1024 + tid];
        unsigned long long b = __ballot(a > 0);
        if (lane == 0) mask[(size_t)row * NW + i * 4 + wave] = b;
    }
}

// ---------------- K1: h = x@W, f1 = h@a1, f2 = h@a2 for 4 heads ----------------
// rec1g is SoA of float4: plane r (r=0..8), each of N entries.
//   r=0:      {f2[h0], f2[h1], f2[h2], f2[h3]}
//   r=1+2h:   {h[h][0..3]}   r=2+2h: {h[h][4..7]}
__global__ void k1_feat(const float* __restrict__ x, const float* __restrict__ Wh,
                        const float* __restrict__ ah,
                        float4* __restrict__ rec1g, float* __restrict__ f1a) {
    __shared__ float sW[NH * FIN * FH];   // 928
    __shared__ float sa[NH * 2 * FH];     // 64
    int tid = threadIdx.x;
    for (int i = tid; i < NH * FIN * FH; i += blockDim.x) sW[i] = Wh[i];
    for (int i = tid; i < NH * 2 * FH; i += blockDim.x) sa[i] = ah[i];
    __syncthreads();
    int node = blockIdx.x * blockDim.x + tid;
    if (node >= N) return;
    float xr[FIN];
#pragma unroll
    for (int f = 0; f < FIN; f++) xr[f] = x[node * FIN + f];
    float hvAll[NH][FH];
    float f2v[NH];
#pragma unroll
    for (int h = 0; h < NH; h++) {
#pragma unroll
        for (int k = 0; k < FH; k++) {
            float s = 0.f;
#pragma unroll
            for (int f = 0; f < FIN; f++) s += xr[f] * sW[(h * FIN + f) * FH + k];
            hvAll[h][k] = s;
        }
        float f1 = 0.f, f2 = 0.f;
#pragma unroll
        for (int k = 0; k < FH; k++) {
            f1 += hvAll[h][k] * sa[h * 16 + k];
            f2 += hvAll[h][k] * sa[h * 16 + 8 + k];
        }
        f2v[h] = f2;
        f1a[node * 4 + h] = f1;
    }
    rec1g[0 * N + node] = make_float4(f2v[0], f2v[1], f2v[2], f2v[3]);
#pragma unroll
    for (int h = 0; h < NH; h++) {
        rec1g[(1 + 2 * h) * N + node] =
            make_float4(hvAll[h][0], hvAll[h][1], hvAll[h][2], hvAll[h][3]);
        rec1g[(2 + 2 * h) * N + node] =
            make_float4(hvAll[h][4], hvAll[h][5], hvAll[h][6], hvAll[h][7]);
    }
}

// ---------------- K2: per-head global max of f2 (single block) ----------------
__global__ void k2_max4(const float4* __restrict__ rec1g, float* __restrict__ maxf2) {
    __shared__ float red[4][256];
    int tid = threadIdx.x;
    float m[4] = {-1e30f, -1e30f, -1e30f, -1e30f};
    for (int j = tid; j < N; j += 256) {
        float4 q = rec1g[j];   // plane 0
        m[0] = fmaxf(m[0], q.x); m[1] = fmaxf(m[1], q.y);
        m[2] = fmaxf(m[2], q.z); m[3] = fmaxf(m[3], q.w);
    }
#pragma unroll
    for (int h = 0; h < 4; h++) red[h][tid] = m[h];
    __syncthreads();
    for (int s = 128; s > 0; s >>= 1) {
        if (tid < s) {
#pragma unroll
            for (int h = 0; h < 4; h++) red[h][tid] = fmaxf(red[h][tid], red[h][tid + s]);
        }
        __syncthreads();
    }
    if (tid < 4) maxf2[tid] = red[tid][0];
}

// ---------------- K3: layer-1 attention, 8 waves x 2 rows = 16 rows/block ----------------
#define TJ 256
__global__ __launch_bounds__(512) void k3_attn1(
    const unsigned long long* __restrict__ mask, const float4* __restrict__ rec1g,
    const float* __restrict__ f1a, const float* __restrict__ maxf2,
    float* __restrict__ hcat) {
    __shared__ float4 tile[9][TJ];  // 36 KB, SoA: conflict-free b128 reads
    int tid = threadIdx.x;
    int lane = tid & 63;
    int wave = tid >> 6;
    int r0 = blockIdx.x * 16 + wave * 2;
    int r1 = r0 + 1;

    float f1_0[NH], f1_1[NH], m0[NH], m1[NH];
#pragma unroll
    for (int h = 0; h < NH; h++) {
        f1_0[h] = f1a[r0 * 4 + h];
        f1_1[h] = f1a[r1 * 4 + h];
        float mf = maxf2[h];
        float v0 = f1_0[h] + mf; m0[h] = fmaxf(v0, ALPHA * v0);
        float v1 = f1_1[h] + mf; m1[h] = fmaxf(v1, ALPHA * v1);
    }
    float acc0[NH][FH + 1], acc1[NH][FH + 1];
#pragma unroll
    for (int h = 0; h < NH; h++)
#pragma unroll
        for (int k = 0; k <= FH; k++) { acc0[h][k] = 0.f; acc1[h][k] = 0.f; }

    const unsigned long long* mrow0 = mask + (size_t)r0 * NW;
    const unsigned long long* mrow1 = mask + (size_t)r1 * NW;

    for (int t = 0; t < N / TJ; t++) {   // 32
        __syncthreads();
        // stage SoA global -> SoA LDS (coalesced, conflict-free)
        for (int i = tid; i < 9 * TJ; i += 512) {
            int r = i >> 8;      // /TJ
            int jl = i & (TJ - 1);
            tile[r][jl] = rec1g[r * N + t * TJ + jl];
        }
        __syncthreads();
#pragma unroll
        for (int s = 0; s < TJ / 64; s++) {  // 4
            int widx = t * (TJ / 64) + s;
            unsigned long long mw0 = mrow0[widx];
            unsigned long long mw1 = mrow1[widx];
            bool b0 = (mw0 >> lane) & 1ull;
            bool b1 = (mw1 >> lane) & 1ull;
            int jl = s * 64 + lane;
            float rv[36];
#pragma unroll
            for (int r = 0; r < 9; r++) {
                float4 q = tile[r][jl];
                rv[4 * r + 0] = q.x; rv[4 * r + 1] = q.y;
                rv[4 * r + 2] = q.z; rv[4 * r + 3] = q.w;
            }
#pragma unroll
            for (int h = 0; h < NH; h++) {
                float e0 = f1_0[h] + rv[h]; e0 = fmaxf(e0, ALPHA * e0);
                float e1 = f1_1[h] + rv[h]; e1 = fmaxf(e1, ALPHA * e1);
                float w0 = b0 ? __expf(e0 - m0[h]) : 0.f;
                float w1 = b1 ? __expf(e1 - m1[h]) : 0.f;
#pragma unroll
                for (int k = 0; k < FH; k++) {
                    acc0[h][k] += w0 * rv[4 + h * 8 + k];
                    acc1[h][k] += w1 * rv[4 + h * 8 + k];
                }
                acc0[h][FH] += w0;
                acc1[h][FH] += w1;
            }
        }
    }
    // butterfly reduce across 64 lanes
#pragma unroll
    for (int h = 0; h < NH; h++)
#pragma unroll
        for (int k = 0; k <= FH; k++) {
            for (int off = 32; off > 0; off >>= 1) {
                acc0[h][k] += __shfl_xor(acc0[h][k], off, 64);
                acc1[h][k] += __shfl_xor(acc1[h][k], off, 64);
            }
        }
    if (lane == 0) {
#pragma unroll
        for (int h = 0; h < NH; h++) {
            float inv0 = 1.f / acc0[h][FH];
            float inv1 = 1.f / acc1[h][FH];
#pragma unroll
            for (int k = 0; k < FH; k++) {
                float o0 = acc0[h][k] * inv0;
                float o1 = acc1[h][k] * inv1;
                o0 = (o0 > 0.f) ? o0 : expm1f(o0);
                o1 = (o1 > 0.f) ? o1 : expm1f(o1);
                hcat[r0 * 32 + h * 8 + k] = o0;
                hcat[r1 * 32 + h * 8 + k] = o1;
            }
        }
    }
}

// ---------------- K4: layer-2 features: h2 = hcat@W_out, f1/f2 ----------------
__global__ void k4_feat2(const float* __restrict__ hcat, const float* __restrict__ Wo,
                         const float* __restrict__ ao,
                         float4* __restrict__ rec2, float* __restrict__ f1b) {
    __shared__ float sW[64];
    __shared__ float sa[4];
    int tid = threadIdx.x;
    if (tid < 64) sW[tid] = Wo[tid];
    if (tid < 4) sa[tid] = ao[tid];
    __syncthreads();
    int node = blockIdx.x * blockDim.x + tid;
    if (node >= N) return;
    float h0 = 0.f, h1 = 0.f;
#pragma unroll
    for (int i = 0; i < 32; i++) {
        float v = hcat[node * 32 + i];
        h0 += v * sW[i * 2 + 0];
        h1 += v * sW[i * 2 + 1];
    }
    float f1 = h0 * sa[0] + h1 * sa[1];
    float f2 = h0 * sa[2] + h1 * sa[3];
    rec2[node] = make_float4(f2, h0, h1, 0.f);
    f1b[node] = f1;
}

// ---------------- K5: global max of f2 (layer 2) ----------------
__global__ void k5_max1(const float4* __restrict__ rec2, float* __restrict__ maxf2b) {
    __shared__ float red[256];
    int tid = threadIdx.x;
    float m = -1e30f;
    for (int j = tid; j < N; j += 256) m = fmaxf(m, rec2[j].x);
    red[tid] = m;
    __syncthreads();
    for (int s = 128; s > 0; s >>= 1) {
        if (tid < s) red[tid] = fmaxf(red[tid], red[tid + s]);
        __syncthreads();
    }
    if (tid == 0) maxf2b[0] = red[0];
}

// ---------------- K6: layer-2 attention + elu + log_softmax ----------------
// 256-thread blocks (4 waves), 4 rows/wave -> 16 rows/block, 512 blocks
#define TJ2 1024
__global__ __launch_bounds__(256) void k6_attn2(
    const unsigned long long* __restrict__ mask, const float4* __restrict__ rec2,
    const float* __restrict__ f1b, const float* __restrict__ maxf2b,
    float* __restrict__ out) {
    __shared__ float4 tile[TJ2];  // 16 KB
    int tid = threadIdx.x;
    int lane = tid & 63;
    int wave = tid >> 6;
    int rbase = blockIdx.x * 16 + wave * 4;

    float f1r[4], mr[4];
#pragma unroll
    for (int i = 0; i < 4; i++) {
        f1r[i] = f1b[rbase + i];
        float v = f1r[i] + maxf2b[0];
        mr[i] = fmaxf(v, ALPHA * v);
    }
    float acc[4][3];
#pragma unroll
    for (int i = 0; i < 4; i++) { acc[i][0] = 0.f; acc[i][1] = 0.f; acc[i][2] = 0.f; }

    const unsigned long long* mrows[4];
#pragma unroll
    for (int i = 0; i < 4; i++) mrows[i] = mask + (size_t)(rbase + i) * NW;

    for (int t = 0; t < N / TJ2; t++) {  // 8
        __syncthreads();
#pragma unroll
        for (int i = 0; i < TJ2 / 256; i++)  // 4
            tile[tid + i * 256] = rec2[t * TJ2 + tid + i * 256];
        __syncthreads();
#pragma unroll 4
        for (int s = 0; s < TJ2 / 64; s++) {  // 16
            int widx = t * (TJ2 / 64) + s;
            float4 q = tile[s * 64 + lane];
#pragma unroll
            for (int i = 0; i < 4; i++) {
                bool b = (mrows[i][widx] >> lane) & 1ull;
                float e = f1r[i] + q.x;
                e = fmaxf(e, ALPHA * e);
                float w = b ? __expf(e - mr[i]) : 0.f;
                acc[i][0] += w * q.y;
                acc[i][1] += w * q.z;
                acc[i][2] += w;
            }
        }
    }
#pragma unroll
    for (int i = 0; i < 4; i++)
#pragma unroll
        for (int c = 0; c < 3; c++)
            for (int off = 32; off > 0; off >>= 1)
                acc[i][c] += __shfl_xor(acc[i][c], off, 64);
    if (lane == 0) {
#pragma unroll
        for (int i = 0; i < 4; i++) {
            float inv = 1.f / acc[i][2];
            float e0 = acc[i][0] * inv;
            float e1 = acc[i][1] * inv;
            e0 = (e0 > 0.f) ? e0 : expm1f(e0);
            e1 = (e1 > 0.f) ? e1 : expm1f(e1);
            float mx = fmaxf(e0, e1);
            float lse = mx + logf(__expf(e0 - mx) + __expf(e1 - mx));
            out[(rbase + i) * 2 + 0] = e0 - lse;
            out[(rbase + i) * 2 + 1] = e1 - lse;
        }
    }
}

extern "C" void kernel_launch(void* const* d_in, const int* in_sizes, int n_in,
                              void* d_out, int out_size, void* d_ws, size_t ws_size,
                              hipStream_t stream) {
    const float* x   = (const float*)d_in[0];
    const int*   adj = (const int*)d_in[1];
    const float* Wh  = (const float*)d_in[2];
    const float* ah  = (const float*)d_in[3];
    const float* Wo  = (const float*)d_in[4];
    const float* ao  = (const float*)d_in[5];
    float* out = (float*)d_out;
    float* ws = (float*)d_ws;

    // workspace layout (floats)
    float4* rec1g = (float4*)ws;                   // 9*N float4  = 294912 floats
    float*  f1a   = ws + 294912;                   // N*4
    float*  hcat  = ws + 327680;                   // N*32
    float4* rec2  = (float4*)(ws + 589824);        // N float4 = 32768 floats
    float*  f1b   = ws + 622592;                   // N
    float*  mf2   = ws + 630784;                   // 4
    float*  mf2b  = ws + 630788;                   // 1
    unsigned long long* mask = (unsigned long long*)(ws + 630800);  // 8 MB

    k0_pack<<<N, 256, 0, stream>>>(adj, mask);
    k1_feat<<<N / 256, 256, 0, stream>>>(x, Wh, ah, rec1g, f1a);
    k2_max4<<<1, 256, 0, stream>>>(rec1g, mf2);
    k3_attn1<<<N / 16, 512, 0, stream>>>(mask, rec1g, f1a, mf2, hcat);
    k4_feat2<<<N / 256, 256, 0, stream>>>(hcat, Wo, ao, rec2, f1b);
    k5_max1<<<1, 256, 0, stream>>>(rec2, mf2b);
    k6_attn2<<<N / 16, 256, 0, stream>>>(mask, rec2, f1b, mf2b, out);
}